// Round 6
// baseline (1933.782 us; speedup 1.0000x reference)
//
#include <hip/hip_runtime.h>

#define RANK  32
#define DIM   128
#define BATCH 64            // rows per BLOCK-level batch
#define GROUPS (BATCH / 8)  // 8 global_load_lds ops per batch (8 rows / 1KB)

// Round-6: add a 2-phase double-buffered pipeline to the round-5 structure.
// Round 5 (145.7us) was serial per batch: sync -> idx load -> gather ->
// vmcnt(0) (~600-900cy exposed) -> sync -> compute. Now: ONE barrier per
// batch; gathers for batch b+stride are issued right after the barrier and
// fly during compute of batch b; idx is prefetched TWO iterations ahead so
// its latency never sits inside the drain. Per-iter serial overhead ~= one
// barrier. Everything else (dim-split waves, 32-float register-pinned w2r,
// 64-VGPR occupancy class) is unchanged from round 5.
__global__ __launch_bounds__(256, 8) void lowrank_emb_kernel(
    const int* __restrict__ idx,
    const float* __restrict__ W1,
    const float* __restrict__ W2,
    float* __restrict__ out,
    int n_rows)
{
  __shared__ float bbuf[2][BATCH * RANK];  // 2 x 8KB

  const int lane        = threadIdx.x & 63;
  const int waveInBlock = threadIdx.x >> 6;
  const int dhalf       = waveInBlock & 1;   // which 64-dim half
  const int rhalf       = waveInBlock >> 1;  // which 32-row half
  const int dim         = dhalf * 64 + lane; // this lane's output dim

  // Per-lane W2 column (32 VGPRs), pinned (round-1 lesson: blocks remat;
  // round-4 lesson: 32 floats fits the 64-VGPR class, 64 floats spills).
  float w2r[RANK];
#pragma unroll
  for (int k = 0; k < RANK; ++k) w2r[k] = W2[k * DIM + dim];
#pragma unroll
  for (int k = 0; k < RANK; ++k) asm("" : "+v"(w2r[k]));

  const int rsub  = lane >> 3;  // row within an 8-row gather group
  const int chunk = lane & 7;   // 16B chunk within a row

  const int nBatches = (n_rows + BATCH - 1) / BATCH;
  const int nBlocks  = gridDim.x;
  const int lastIdx  = n_rows - 1;

  auto issueGather = [&](int iv, float* dst) {
    // This wave issues 2 of the block's 8 groups; lane l fetches 16B chunk
    // (l&7) of group-row (l>>3); HW writes base+l*16 = row-major [8][32] f32.
#pragma unroll
    for (int gi = 0; gi < GROUPS / 4; ++gi) {
      const int g = waveInBlock * (GROUPS / 4) + gi;
      const int e = __shfl(iv, g * 8 + rsub, 64);
      const float* src = W1 + (size_t)e * RANK + chunk * 4;
      __builtin_amdgcn_global_load_lds(
          (const __attribute__((address_space(1))) unsigned*)src,
          (__attribute__((address_space(3))) unsigned*)(dst + g * (8 * RANK)),
          16, 0, 0);
    }
  };

  int b = blockIdx.x;
  if (b >= nBatches) return;  // block-uniform: all 4 waves exit together

  // Prologue: gather batch b now; prefetch idx for b+nBlocks.
  {
    const int r = b * BATCH + lane;
    const int iv0 = idx[r < n_rows ? r : lastIdx];
    issueGather(iv0, bbuf[0]);
  }
  int ivNext;  // idx for batch b+nBlocks (in flight / ready)
  {
    const int r = (b + nBlocks) * BATCH + lane;
    ivNext = idx[(r < n_rows && (b + nBlocks) < nBatches) ? r : lastIdx];
  }

  int parity = 0;
  for (; b < nBatches; b += nBlocks, parity ^= 1) {
    const int bn = b + nBlocks;

    // Drain: gathers for b (issued one full compute ago), ivNext, and the
    // previous compute's stores — all should be complete or nearly so.
    asm volatile("s_waitcnt vmcnt(0)" ::: "memory");
    __builtin_amdgcn_sched_barrier(0);
    __syncthreads();                      // bbuf[parity] visible to all waves;
    __builtin_amdgcn_sched_barrier(0);    // pin gather issue BELOW the barrier

    // Issue next batch's gathers into the other buffer; they fly over compute.
    if (bn < nBatches) issueGather(ivNext, bbuf[parity ^ 1]);

    // Prefetch idx for b+2*nBlocks (drains at the NEXT iteration top).
    {
      const int b2 = b + 2 * nBlocks;
      const int r = b2 * BATCH + lane;
      ivNext = idx[(b2 < nBatches && r < n_rows) ? r : lastIdx];
    }

    // Compute my 32 rows x my 64-dim half from bbuf[parity]: per row, 8
    // broadcast (same-address, conflict-free) ds_read_b128 + 32 FMAs + one
    // 256B coalesced store.
    const float* buf = bbuf[parity];
    const int rowBase = b * BATCH;
    const int r0 = rhalf * 32;
    if (rowBase + BATCH <= n_rows) {
#pragma unroll 2
      for (int r = 0; r < 32; ++r) {
        const float4* rowp = reinterpret_cast<const float4*>(buf + (r0 + r) * RANK);
        float a0 = 0.f, a1 = 0.f;
#pragma unroll
        for (int c = 0; c < 8; ++c) {
          const float4 f = rowp[c];
          a0 = fmaf(f.x, w2r[4 * c + 0], a0);
          a1 = fmaf(f.y, w2r[4 * c + 1], a1);
          a0 = fmaf(f.z, w2r[4 * c + 2], a0);
          a1 = fmaf(f.w, w2r[4 * c + 3], a1);
        }
        out[(size_t)(rowBase + r0 + r) * DIM + dim] = a0 + a1;
      }
    } else {
      for (int r = 0; r < 32; ++r) {
        const int orow = rowBase + r0 + r;
        if (orow >= n_rows) break;
        const float4* rowp = reinterpret_cast<const float4*>(buf + (r0 + r) * RANK);
        float a0 = 0.f, a1 = 0.f;
#pragma unroll
        for (int c = 0; c < 8; ++c) {
          const float4 f = rowp[c];
          a0 = fmaf(f.x, w2r[4 * c + 0], a0);
          a1 = fmaf(f.y, w2r[4 * c + 1], a1);
          a0 = fmaf(f.z, w2r[4 * c + 2], a0);
          a1 = fmaf(f.w, w2r[4 * c + 3], a1);
        }
        out[(size_t)orow * DIM + dim] = a0 + a1;
      }
    }
  }
}

extern "C" void kernel_launch(void* const* d_in, const int* in_sizes, int n_in,
                              void* d_out, int out_size, void* d_ws, size_t ws_size,
                              hipStream_t stream) {
  const int*   idx = (const int*)d_in[0];   // [4096*200]
  const float* W1  = (const float*)d_in[1]; // [1e6, 32]
  const float* W2  = (const float*)d_in[2]; // [32, 128]
  float*       out = (float*)d_out;         // [4096*200, 128]
  const int n_rows = in_sizes[0];

  const int threads = 256;   // 4 waves/block
  const int blocks  = 2048;  // 8 blocks/CU resident; grid-stride over batches
  hipLaunchKernelGGL(lowrank_emb_kernel, dim3(blocks), dim3(threads), 0, stream,
                     idx, W1, W2, out, n_rows);
}

// Round 7
// 199.679 us; speedup vs baseline: 9.6844x; 9.6844x over previous
//
#include <hip/hip_runtime.h>

#define RANK  32
#define DIM   128
#define BATCH 64            // rows per BLOCK-level batch
#define GROUPS (BATCH / 8)  // 8 global_load_lds ops per batch (8 rows / 1KB)

// Round-7: round 6's pipeline was correct but died of spills: the 64-VGPR cap
// from __launch_bounds__(256,8) could not hold w2r + pipeline state (FETCH
// 6.25GB of scratch reloads, VGPR_Count=32). This kernel's working set
// belongs in the 128-VGPR / 4-waves-per-SIMD class. amdgpu_waves_per_eu(4,4)
// pins BOTH min and max: budget 128 VGPRs, and no occupancy incentive for the
// allocator to shrink-and-spill (the round-4 failure mode). Double-buffered
// LDS supplies the latency hiding the lost TLP used to.
__global__ __launch_bounds__(256)
__attribute__((amdgpu_waves_per_eu(4, 4)))
void lowrank_emb_kernel(
    const int* __restrict__ idx,
    const float* __restrict__ W1,
    const float* __restrict__ W2,
    float* __restrict__ out,
    int n_rows)
{
  __shared__ float bbuf[2][BATCH * RANK];  // 2 x 8KB

  const int lane        = threadIdx.x & 63;
  const int waveInBlock = threadIdx.x >> 6;
  const int dhalf       = waveInBlock & 1;   // which 64-dim half
  const int rhalf       = waveInBlock >> 1;  // which 32-row half
  const int dim         = dhalf * 64 + lane; // this lane's output dim

  // Per-lane W2 column (32 VGPRs), pinned (round-1 lesson: blocks remat).
  float w2r[RANK];
#pragma unroll
  for (int k = 0; k < RANK; ++k) w2r[k] = W2[k * DIM + dim];
#pragma unroll
  for (int k = 0; k < RANK; ++k) asm("" : "+v"(w2r[k]));

  const int rsub  = lane >> 3;  // row within an 8-row gather group
  const int chunk = lane & 7;   // 16B chunk within a row

  const int nBatches = (n_rows + BATCH - 1) / BATCH;
  const int nBlocks  = gridDim.x;
  const int lastIdx  = n_rows - 1;

  auto issueGather = [&](int iv, float* dst) {
    // This wave issues 2 of the block's 8 groups; lane l fetches 16B chunk
    // (l&7) of group-row (l>>3); HW writes base+l*16 = row-major [8][32] f32.
#pragma unroll
    for (int gi = 0; gi < GROUPS / 4; ++gi) {
      const int g = waveInBlock * (GROUPS / 4) + gi;
      const int e = __shfl(iv, g * 8 + rsub, 64);
      const float* src = W1 + (size_t)e * RANK + chunk * 4;
      __builtin_amdgcn_global_load_lds(
          (const __attribute__((address_space(1))) unsigned*)src,
          (__attribute__((address_space(3))) unsigned*)(dst + g * (8 * RANK)),
          16, 0, 0);
    }
  };

  int b = blockIdx.x;
  if (b >= nBatches) return;  // block-uniform: all 4 waves exit together

  // Prologue: gather batch b now; prefetch idx for b+nBlocks.
  {
    const int r = b * BATCH + lane;
    const int iv0 = idx[r < n_rows ? r : lastIdx];
    issueGather(iv0, bbuf[0]);
  }
  int ivNext;  // idx for batch b+nBlocks (in flight / ready)
  {
    const int r = (b + nBlocks) * BATCH + lane;
    ivNext = idx[(r < n_rows && (b + nBlocks) < nBatches) ? r : lastIdx];
  }

  int parity = 0;
  for (; b < nBatches; b += nBlocks, parity ^= 1) {
    const int bn = b + nBlocks;

    // Drain: gathers for b (issued one full compute phase ago) + ivNext.
    asm volatile("s_waitcnt vmcnt(0)" ::: "memory");
    __builtin_amdgcn_sched_barrier(0);
    __syncthreads();                      // bbuf[parity] visible to all waves;
    __builtin_amdgcn_sched_barrier(0);    // pin gather issue BELOW the barrier

    // Issue next batch's gathers into the other buffer; they fly over compute.
    if (bn < nBatches) issueGather(ivNext, bbuf[parity ^ 1]);

    // Prefetch idx for b+2*nBlocks (drains at the NEXT iteration top).
    {
      const int b2 = b + 2 * nBlocks;
      const int r = b2 * BATCH + lane;
      ivNext = idx[(b2 < nBatches && r < n_rows) ? r : lastIdx];
    }

    // Compute my 32 rows x my 64-dim half from bbuf[parity]: per row, 8
    // broadcast (same-address, conflict-free) ds_read_b128 + 32 FMAs + one
    // 256B coalesced store.
    const float* buf = bbuf[parity];
    const int rowBase = b * BATCH;
    const int r0 = rhalf * 32;
    if (rowBase + BATCH <= n_rows) {
#pragma unroll 2
      for (int r = 0; r < 32; ++r) {
        const float4* rowp = reinterpret_cast<const float4*>(buf + (r0 + r) * RANK);
        float a0 = 0.f, a1 = 0.f;
#pragma unroll
        for (int c = 0; c < 8; ++c) {
          const float4 f = rowp[c];
          a0 = fmaf(f.x, w2r[4 * c + 0], a0);
          a1 = fmaf(f.y, w2r[4 * c + 1], a1);
          a0 = fmaf(f.z, w2r[4 * c + 2], a0);
          a1 = fmaf(f.w, w2r[4 * c + 3], a1);
        }
        out[(size_t)(rowBase + r0 + r) * DIM + dim] = a0 + a1;
      }
    } else {
      for (int r = 0; r < 32; ++r) {
        const int orow = rowBase + r0 + r;
        if (orow >= n_rows) break;
        const float4* rowp = reinterpret_cast<const float4*>(buf + (r0 + r) * RANK);
        float a0 = 0.f, a1 = 0.f;
#pragma unroll
        for (int c = 0; c < 8; ++c) {
          const float4 f = rowp[c];
          a0 = fmaf(f.x, w2r[4 * c + 0], a0);
          a1 = fmaf(f.y, w2r[4 * c + 1], a1);
          a0 = fmaf(f.z, w2r[4 * c + 2], a0);
          a1 = fmaf(f.w, w2r[4 * c + 3], a1);
        }
        out[(size_t)orow * DIM + dim] = a0 + a1;
      }
    }
  }
}

extern "C" void kernel_launch(void* const* d_in, const int* in_sizes, int n_in,
                              void* d_out, int out_size, void* d_ws, size_t ws_size,
                              hipStream_t stream) {
  const int*   idx = (const int*)d_in[0];   // [4096*200]
  const float* W1  = (const float*)d_in[1]; // [1e6, 32]
  const float* W2  = (const float*)d_in[2]; // [32, 128]
  float*       out = (float*)d_out;         // [4096*200, 128]
  const int n_rows = in_sizes[0];

  const int threads = 256;   // 4 waves/block
  const int blocks  = 1024;  // exactly resident at 4 blocks/CU; ~12.5 batches each
  hipLaunchKernelGGL(lowrank_emb_kernel, dim3(blocks), dim3(threads), 0, stream,
                     idx, W1, W2, out, n_rows);
}